// Round 3
// baseline (510.198 us; speedup 1.0000x reference)
//
#include <hip/hip_runtime.h>
#include <hip/hip_bf16.h>
#include <stdint.h>

// MHA forward: B=4, S=2048, D=512, H=8, HD=64. f32 in/out, bf16 MFMA internally.
// out0 = out [B,S,D] f32, out1 = attn [B,H,S,S] f32 (concatenated in d_out).

typedef __attribute__((ext_vector_type(8))) short bf16x8;
typedef __attribute__((ext_vector_type(4))) short bf16x4;
typedef __attribute__((ext_vector_type(4))) float f32x4;

#define MFMA16(a, b, c) __builtin_amdgcn_mfma_f32_16x16x32_bf16((a), (b), (c), 0, 0, 0)

__device__ __forceinline__ unsigned short f2bf(float f) {
  unsigned u = __float_as_uint(f);
  u += 0x7FFFu + ((u >> 16) & 1u);   // RNE
  return (unsigned short)(u >> 16);
}
__device__ __forceinline__ float bf2f(unsigned short u) {
  return __uint_as_float(((unsigned)u) << 16);
}

// ---------------------------------------------------------------------------
// Kernel 1: fused QKV projection. z = 0,1,2 -> q,k,v.
// q,k written as [B,H,S,HD] bf16; v written transposed [B,H,HD,S] bf16.
// ---------------------------------------------------------------------------
__global__ __launch_bounds__(256) void k_proj_qkv(
    const float* __restrict__ q_in, const float* __restrict__ k_in,
    const float* __restrict__ v_in,
    const float* __restrict__ Wq, const float* __restrict__ bq,
    const float* __restrict__ Wk, const float* __restrict__ bk,
    const float* __restrict__ Wv, const float* __restrict__ bv,
    unsigned short* __restrict__ q_ws, unsigned short* __restrict__ k_ws,
    unsigned short* __restrict__ vt_ws)
{
  const int z = blockIdx.z;
  const float* X    = (z == 0) ? q_in : (z == 1) ? k_in : v_in;
  const float* W    = (z == 0) ? Wq   : (z == 1) ? Wk   : Wv;
  const float* bias = (z == 0) ? bq   : (z == 1) ? bk   : bv;
  unsigned short* out = (z == 0) ? q_ws : (z == 1) ? k_ws : vt_ws;

  __shared__ unsigned short As[128][72];
  __shared__ unsigned short Bs[128][72];

  const int t = threadIdx.x;
  const int lane = t & 63;
  const int w = t >> 6;
  const int wr = w >> 1, wc = w & 1;
  const int mbase = blockIdx.x * 128;
  const int nbase = blockIdx.y * 128;

  f32x4 acc[4][4] = {};

  for (int kb = 0; kb < 512; kb += 64) {
    __syncthreads();
#pragma unroll
    for (int i = 0; i < 4; ++i) {
      int chunk = i * 256 + t;
      int row = chunk >> 3;
      int c8 = (chunk & 7) * 8;
      const float* ga = X + (size_t)(mbase + row) * 512 + kb + c8;
      float4 a0 = *(const float4*)ga;
      float4 a1 = *(const float4*)(ga + 4);
      bf16x8 pa;
      pa[0] = (short)f2bf(a0.x); pa[1] = (short)f2bf(a0.y);
      pa[2] = (short)f2bf(a0.z); pa[3] = (short)f2bf(a0.w);
      pa[4] = (short)f2bf(a1.x); pa[5] = (short)f2bf(a1.y);
      pa[6] = (short)f2bf(a1.z); pa[7] = (short)f2bf(a1.w);
      *(bf16x8*)&As[row][c8] = pa;
      const float* gb = W + (size_t)(nbase + row) * 512 + kb + c8;
      float4 b0 = *(const float4*)gb;
      float4 b1 = *(const float4*)(gb + 4);
      bf16x8 pb;
      pb[0] = (short)f2bf(b0.x); pb[1] = (short)f2bf(b0.y);
      pb[2] = (short)f2bf(b0.z); pb[3] = (short)f2bf(b0.w);
      pb[4] = (short)f2bf(b1.x); pb[5] = (short)f2bf(b1.y);
      pb[6] = (short)f2bf(b1.z); pb[7] = (short)f2bf(b1.w);
      *(bf16x8*)&Bs[row][c8] = pb;
    }
    __syncthreads();
#pragma unroll
    for (int kk = 0; kk < 64; kk += 32) {
      bf16x8 af[4], bfr[4];
#pragma unroll
      for (int mi = 0; mi < 4; ++mi)
        af[mi] = *(const bf16x8*)&As[wr * 64 + mi * 16 + (lane & 15)][kk + (lane >> 4) * 8];
#pragma unroll
      for (int ni = 0; ni < 4; ++ni)
        bfr[ni] = *(const bf16x8*)&Bs[wc * 64 + ni * 16 + (lane & 15)][kk + (lane >> 4) * 8];
#pragma unroll
      for (int mi = 0; mi < 4; ++mi)
#pragma unroll
        for (int ni = 0; ni < 4; ++ni)
          acc[mi][ni] = MFMA16(af[mi], bfr[ni], acc[mi][ni]);
    }
  }

#pragma unroll
  for (int ni = 0; ni < 4; ++ni) {
    int n = nbase + wc * 64 + ni * 16 + (lane & 15);
    float bv_ = bias[n];
    int h = n >> 6, hd = n & 63;
#pragma unroll
    for (int mi = 0; mi < 4; ++mi) {
#pragma unroll
      for (int i = 0; i < 4; ++i) {
        int m = mbase + wr * 64 + mi * 16 + (lane >> 4) * 4 + i;
        int b_ = m >> 11, s = m & 2047;
        float val = acc[mi][ni][i] + bv_;
        size_t off;
        if (z < 2) off = ((size_t)(b_ * 8 + h) * 2048 + s) * 64 + hd;      // [B,H,S,HD]
        else       off = ((size_t)(b_ * 8 + h) * 64 + hd) * 2048 + s;      // [B,H,HD,S]
        out[off] = f2bf(val);
      }
    }
  }
}

// ---------------------------------------------------------------------------
// Kernel 2: attention. Block = (b,h) x 16 q-rows, 8 waves (512 thr).
// Wave w owns k-cols [w*256, w*256+256). SWAPPED QK^T: mfma(K,Q) gives
// C[k][q] -> lane (lo=q, hi) holds 4 CONSECUTIVE k for its own q row.
// exp(P) kept bf16-packed in 32 VGPR; PV consumes the pairs directly via
// zero-padded 16x16x32 MFMA (no LDS, no cross-lane). attn written with plain
// float4 stores (L2 write-combining -> exact bytes).
// ---------------------------------------------------------------------------
__global__ __launch_bounds__(512) void k_attn(
    const unsigned short* __restrict__ q_ws, const unsigned short* __restrict__ k_ws,
    const unsigned short* __restrict__ vt_ws, unsigned short* __restrict__ o_ws,
    float* __restrict__ attn_out)
{
  __shared__ float o_red[8][16][68];            // per-wave O partials (+4 pad)
  __shared__ float wsum[8][16];
  __shared__ float rinv_s[16];

  const int t = threadIdx.x;
  const int lane = t & 63;
  const int w = t >> 6;            // 0..7
  const int lo = lane & 15;
  const int hi = lane >> 4;        // 0..3
  const int bh = blockIdx.y;       // 0..31
  const int qbase = blockIdx.x * 16;
  const size_t qk_base = (size_t)bh * 2048 * 64;
  const int kw = w * 256;          // wave's k range

  // Q fragments (B operand: col = q = lo, d = hi*8 + j)
  bf16x8 qf0 = *(const bf16x8*)(q_ws + qk_base + (size_t)(qbase + lo) * 64 + hi * 8);
  bf16x8 qf1 = *(const bf16x8*)(q_ws + qk_base + (size_t)(qbase + lo) * 64 + 32 + hi * 8);

  unsigned p_pk[16][2];            // packed bf16 pairs: k = tile*16 + hi*4 + (0..3), q = lo
  f32x4 o_acc[4] = {};             // [hd-tile]: rows q = hi*4+i, col hd = hdt*16+lo
  float srow = 0.f;                // partial row sum for q = lo

#pragma unroll
  for (int t2 = 0; t2 < 16; ++t2) {
    const int cb = kw + t2 * 16;
    // --- QK^T (swapped): A = K rows (k), B = Q cols (q) ---
    const unsigned short* kp = k_ws + qk_base + (size_t)(cb + lo) * 64 + hi * 8;
    bf16x8 kf0 = *(const bf16x8*)kp;
    bf16x8 kf1 = *(const bf16x8*)(kp + 32);
    f32x4 c = {};
    c = MFMA16(kf0, qf0, c);
    c = MFMA16(kf1, qf1, c);
    float e0 = __expf(c[0] * 0.125f);
    float e1 = __expf(c[1] * 0.125f);
    float e2 = __expf(c[2] * 0.125f);
    float e3 = __expf(c[3] * 0.125f);
    srow += (e0 + e1) + (e2 + e3);
    unsigned w0 = (unsigned)f2bf(e0) | ((unsigned)f2bf(e1) << 16);
    unsigned w1 = (unsigned)f2bf(e2) | ((unsigned)f2bf(e3) << 16);
    p_pk[t2][0] = w0;
    p_pk[t2][1] = w1;

    // --- PV partial: A = P pairs (real k in slots 0..3 of each 8-group) ---
    bf16x8 pa8;
    pa8[0] = (short)(w0 & 0xffffu); pa8[1] = (short)(w0 >> 16);
    pa8[2] = (short)(w1 & 0xffffu); pa8[3] = (short)(w1 >> 16);
    pa8[4] = 0; pa8[5] = 0; pa8[6] = 0; pa8[7] = 0;
#pragma unroll
    for (int hdt = 0; hdt < 4; ++hdt) {
      bf16x4 v4 = *(const bf16x4*)(vt_ws +
          (size_t)(bh * 64 + hdt * 16 + lo) * 2048 + cb + hi * 4);
      bf16x8 vb8;
      vb8[0] = v4[0]; vb8[1] = v4[1]; vb8[2] = v4[2]; vb8[3] = v4[3];
      vb8[4] = 0; vb8[5] = 0; vb8[6] = 0; vb8[7] = 0;
      o_acc[hdt] = MFMA16(pa8, vb8, o_acc[hdt]);
    }
  }

  // --- row sums: lanes sharing lo hold partials for the same q ---
  srow += __shfl_xor(srow, 16, 64);
  srow += __shfl_xor(srow, 32, 64);
  if (hi == 0) wsum[w][lo] = srow;
  // --- stash O partials ---
#pragma unroll
  for (int hdt = 0; hdt < 4; ++hdt)
#pragma unroll
    for (int i = 0; i < 4; ++i)
      o_red[w][hi * 4 + i][hdt * 16 + lo] = o_acc[hdt][i];
  __syncthreads();
  if (t < 16) {
    float s = 0.f;
#pragma unroll
    for (int ww = 0; ww < 8; ++ww) s += wsum[ww][t];
    rinv_s[t] = 1.0f / s;
  }
  __syncthreads();

  // --- O write (reduce 8 wave partials, normalize, bf16) ---
  {
    const int b_ = bh >> 3, h = bh & 7;
#pragma unroll
    for (int e = 0; e < 2; ++e) {
      int idx = t + e * 512;       // 0..1023 over [16 q][64 hd]
      int q = idx >> 6, hd = idx & 63;
      float s = 0.f;
#pragma unroll
      for (int ww = 0; ww < 8; ++ww) s += o_red[ww][q][hd];
      float val = s * rinv_s[q];
      o_ws[((size_t)(b_ * 2048) + qbase + q) * 512 + h * 64 + hd] = f2bf(val);
    }
  }

  // --- pass 2: normalized attn f32, float4 per lane (contiguous 16B) ---
  {
    float rv = rinv_s[lo];
    float* ao = attn_out + (size_t)bh * 2048 * 2048 +
                (size_t)(qbase + lo) * 2048 + kw + hi * 4;
#pragma unroll
    for (int t2 = 0; t2 < 16; ++t2) {
      unsigned u0 = p_pk[t2][0], u1 = p_pk[t2][1];
      float4 o;
      o.x = bf2f((unsigned short)(u0 & 0xffffu)) * rv;
      o.y = bf2f((unsigned short)(u0 >> 16)) * rv;
      o.z = bf2f((unsigned short)(u1 & 0xffffu)) * rv;
      o.w = bf2f((unsigned short)(u1 >> 16)) * rv;
      *(float4*)(ao + t2 * 16) = o;
    }
  }
}

// ---------------------------------------------------------------------------
// Kernel 3: output projection, f32 out.
// ---------------------------------------------------------------------------
__global__ __launch_bounds__(256) void k_proj_out(
    const unsigned short* __restrict__ Ao, const float* __restrict__ Wo,
    const float* __restrict__ bo, float* __restrict__ outp)
{
  __shared__ unsigned short As[128][72];
  __shared__ unsigned short Bs[128][72];

  const int t = threadIdx.x;
  const int lane = t & 63;
  const int w = t >> 6;
  const int wr = w >> 1, wc = w & 1;
  const int mbase = blockIdx.x * 128;
  const int nbase = blockIdx.y * 128;

  f32x4 acc[4][4] = {};

  for (int kb = 0; kb < 512; kb += 64) {
    __syncthreads();
#pragma unroll
    for (int i = 0; i < 4; ++i) {
      int chunk = i * 256 + t;
      int row = chunk >> 3;
      int c8 = (chunk & 7) * 8;
      *(bf16x8*)&As[row][c8] =
          *(const bf16x8*)(Ao + (size_t)(mbase + row) * 512 + kb + c8);
      const float* gb = Wo + (size_t)(nbase + row) * 512 + kb + c8;
      float4 b0 = *(const float4*)gb;
      float4 b1 = *(const float4*)(gb + 4);
      bf16x8 pb;
      pb[0] = (short)f2bf(b0.x); pb[1] = (short)f2bf(b0.y);
      pb[2] = (short)f2bf(b0.z); pb[3] = (short)f2bf(b0.w);
      pb[4] = (short)f2bf(b1.x); pb[5] = (short)f2bf(b1.y);
      pb[6] = (short)f2bf(b1.z); pb[7] = (short)f2bf(b1.w);
      *(bf16x8*)&Bs[row][c8] = pb;
    }
    __syncthreads();
#pragma unroll
    for (int kk = 0; kk < 64; kk += 32) {
      bf16x8 af[4], bfr[4];
#pragma unroll
      for (int mi = 0; mi < 4; ++mi)
        af[mi] = *(const bf16x8*)&As[wr * 64 + mi * 16 + (lane & 15)][kk + (lane >> 4) * 8];
#pragma unroll
      for (int ni = 0; ni < 4; ++ni)
        bfr[ni] = *(const bf16x8*)&Bs[wc * 64 + ni * 16 + (lane & 15)][kk + (lane >> 4) * 8];
#pragma unroll
      for (int mi = 0; mi < 4; ++mi)
#pragma unroll
        for (int ni = 0; ni < 4; ++ni)
          acc[mi][ni] = MFMA16(af[mi], bfr[ni], acc[mi][ni]);
    }
  }

#pragma unroll
  for (int ni = 0; ni < 4; ++ni) {
    int n = nbase + wc * 64 + ni * 16 + (lane & 15);
    float bv_ = bo[n];
#pragma unroll
    for (int mi = 0; mi < 4; ++mi) {
#pragma unroll
      for (int i = 0; i < 4; ++i) {
        int m = mbase + wr * 64 + mi * 16 + (lane >> 4) * 4 + i;
        outp[(size_t)m * 512 + n] = acc[mi][ni][i] + bv_;
      }
    }
  }
}

// ---------------------------------------------------------------------------
extern "C" void kernel_launch(void* const* d_in, const int* in_sizes, int n_in,
                              void* d_out, int out_size, void* d_ws, size_t ws_size,
                              hipStream_t stream) {
  const float* q_in = (const float*)d_in[0];
  const float* k_in = (const float*)d_in[1];
  const float* v_in = (const float*)d_in[2];
  const float* Wq = (const float*)d_in[3];
  const float* bq = (const float*)d_in[4];
  const float* Wk = (const float*)d_in[5];
  const float* bk = (const float*)d_in[6];
  const float* Wv = (const float*)d_in[7];
  const float* bv = (const float*)d_in[8];
  const float* Wo = (const float*)d_in[9];
  const float* bo = (const float*)d_in[10];

  float* out0 = (float*)d_out;                          // [B,S,D] f32
  float* attn = out0 + (size_t)4 * 2048 * 512;          // [B,H,S,S] f32

  unsigned short* ws = (unsigned short*)d_ws;
  const size_t SEG = (size_t)4 * 2048 * 512;
  unsigned short* q_ws  = ws;
  unsigned short* k_ws  = ws + SEG;
  unsigned short* vt_ws = ws + 2 * SEG;
  unsigned short* o_ws  = ws + 3 * SEG;

  dim3 g1(64, 4, 3);
  k_proj_qkv<<<g1, 256, 0, stream>>>(q_in, k_in, v_in, Wq, bq, Wk, bk, Wv, bv,
                                     q_ws, k_ws, vt_ws);
  dim3 g2(128, 32);
  k_attn<<<g2, 512, 0, stream>>>(q_ws, k_ws, vt_ws, o_ws, attn);
  dim3 g3(64, 4);
  k_proj_out<<<g3, 256, 0, stream>>>(o_ws, Wo, bo, out0);
}

// Round 5
// 447.519 us; speedup vs baseline: 1.1401x; 1.1401x over previous
//
#include <hip/hip_runtime.h>
#include <hip/hip_bf16.h>
#include <stdint.h>

// MHA forward: B=4, S=2048, D=512, H=8, HD=64. f32 in/out, bf16 MFMA internally.
// out0 = out [B,S,D] f32, out1 = attn [B,H,S,S] f32 (concatenated in d_out).

typedef __attribute__((ext_vector_type(8))) short bf16x8;
typedef __attribute__((ext_vector_type(4))) short bf16x4;
typedef __attribute__((ext_vector_type(4))) float f32x4;

#define MFMA16(a, b, c) __builtin_amdgcn_mfma_f32_16x16x32_bf16((a), (b), (c), 0, 0, 0)

__device__ __forceinline__ unsigned short f2bf(float f) {
  unsigned u = __float_as_uint(f);
  u += 0x7FFFu + ((u >> 16) & 1u);   // RNE
  return (unsigned short)(u >> 16);
}
__device__ __forceinline__ float bf2f(unsigned short u) {
  return __uint_as_float(((unsigned)u) << 16);
}

// ---------------------------------------------------------------------------
// Kernel 1: fused QKV projection. z = 0,1,2 -> q,k,v.
// q,k written as [B,H,S,HD] bf16; v written transposed [B,H,HD,S] bf16.
// ---------------------------------------------------------------------------
__global__ __launch_bounds__(256) void k_proj_qkv(
    const float* __restrict__ q_in, const float* __restrict__ k_in,
    const float* __restrict__ v_in,
    const float* __restrict__ Wq, const float* __restrict__ bq,
    const float* __restrict__ Wk, const float* __restrict__ bk,
    const float* __restrict__ Wv, const float* __restrict__ bv,
    unsigned short* __restrict__ q_ws, unsigned short* __restrict__ k_ws,
    unsigned short* __restrict__ vt_ws)
{
  const int z = blockIdx.z;
  const float* X    = (z == 0) ? q_in : (z == 1) ? k_in : v_in;
  const float* W    = (z == 0) ? Wq   : (z == 1) ? Wk   : Wv;
  const float* bias = (z == 0) ? bq   : (z == 1) ? bk   : bv;
  unsigned short* out = (z == 0) ? q_ws : (z == 1) ? k_ws : vt_ws;

  __shared__ unsigned short As[128][72];
  __shared__ unsigned short Bs[128][72];

  const int t = threadIdx.x;
  const int lane = t & 63;
  const int w = t >> 6;
  const int wr = w >> 1, wc = w & 1;
  const int mbase = blockIdx.x * 128;
  const int nbase = blockIdx.y * 128;

  f32x4 acc[4][4] = {};

  for (int kb = 0; kb < 512; kb += 64) {
    __syncthreads();
#pragma unroll
    for (int i = 0; i < 4; ++i) {
      int chunk = i * 256 + t;
      int row = chunk >> 3;
      int c8 = (chunk & 7) * 8;
      const float* ga = X + (size_t)(mbase + row) * 512 + kb + c8;
      float4 a0 = *(const float4*)ga;
      float4 a1 = *(const float4*)(ga + 4);
      bf16x8 pa;
      pa[0] = (short)f2bf(a0.x); pa[1] = (short)f2bf(a0.y);
      pa[2] = (short)f2bf(a0.z); pa[3] = (short)f2bf(a0.w);
      pa[4] = (short)f2bf(a1.x); pa[5] = (short)f2bf(a1.y);
      pa[6] = (short)f2bf(a1.z); pa[7] = (short)f2bf(a1.w);
      *(bf16x8*)&As[row][c8] = pa;
      const float* gb = W + (size_t)(nbase + row) * 512 + kb + c8;
      float4 b0 = *(const float4*)gb;
      float4 b1 = *(const float4*)(gb + 4);
      bf16x8 pb;
      pb[0] = (short)f2bf(b0.x); pb[1] = (short)f2bf(b0.y);
      pb[2] = (short)f2bf(b0.z); pb[3] = (short)f2bf(b0.w);
      pb[4] = (short)f2bf(b1.x); pb[5] = (short)f2bf(b1.y);
      pb[6] = (short)f2bf(b1.z); pb[7] = (short)f2bf(b1.w);
      *(bf16x8*)&Bs[row][c8] = pb;
    }
    __syncthreads();
#pragma unroll
    for (int kk = 0; kk < 64; kk += 32) {
      bf16x8 af[4], bfr[4];
#pragma unroll
      for (int mi = 0; mi < 4; ++mi)
        af[mi] = *(const bf16x8*)&As[wr * 64 + mi * 16 + (lane & 15)][kk + (lane >> 4) * 8];
#pragma unroll
      for (int ni = 0; ni < 4; ++ni)
        bfr[ni] = *(const bf16x8*)&Bs[wc * 64 + ni * 16 + (lane & 15)][kk + (lane >> 4) * 8];
#pragma unroll
      for (int mi = 0; mi < 4; ++mi)
#pragma unroll
        for (int ni = 0; ni < 4; ++ni)
          acc[mi][ni] = MFMA16(af[mi], bfr[ni], acc[mi][ni]);
    }
  }

#pragma unroll
  for (int ni = 0; ni < 4; ++ni) {
    int n = nbase + wc * 64 + ni * 16 + (lane & 15);
    float bv_ = bias[n];
    int h = n >> 6, hd = n & 63;
#pragma unroll
    for (int mi = 0; mi < 4; ++mi) {
#pragma unroll
      for (int i = 0; i < 4; ++i) {
        int m = mbase + wr * 64 + mi * 16 + (lane >> 4) * 4 + i;
        int b_ = m >> 11, s = m & 2047;
        float val = acc[mi][ni][i] + bv_;
        size_t off;
        if (z < 2) off = ((size_t)(b_ * 8 + h) * 2048 + s) * 64 + hd;      // [B,H,S,HD]
        else       off = ((size_t)(b_ * 8 + h) * 64 + hd) * 2048 + s;      // [B,H,HD,S]
        out[off] = f2bf(val);
      }
    }
  }
}

// ---------------------------------------------------------------------------
// Kernel 2: attention. Block = (b,h) x 16 q-rows, 8 waves (512 thr).
// Wave w owns k-cols [w*256..+256). Swapped QK^T: mfma(K,Q) -> lane (lo=q,hi)
// holds 4 consecutive k for its own q row. Phase 1: QK^T+exp+rowsum (regs).
// Phase 2: denominator. Phase 3: normalize -> NONTEMPORAL f32x4 attn store
// fused with PV MFMA (full K=32 per MFMA via t2-pairs). Phase 4: O reduce.
// ---------------------------------------------------------------------------
__global__ __launch_bounds__(512) void k_attn(
    const unsigned short* __restrict__ q_ws, const unsigned short* __restrict__ k_ws,
    const unsigned short* __restrict__ vt_ws, unsigned short* __restrict__ o_ws,
    float* __restrict__ attn_out)
{
  __shared__ float o_red[8][16][68];            // per-wave O partials (+4 pad)
  __shared__ float wsum[8][16];
  __shared__ float rinv_s[16];

  const int t = threadIdx.x;
  const int lane = t & 63;
  const int w = t >> 6;            // 0..7
  const int lo = lane & 15;
  const int hi = lane >> 4;        // 0..3
  const int bh = blockIdx.y;       // 0..31
  const int qbase = blockIdx.x * 16;
  const size_t qk_base = (size_t)bh * 2048 * 64;
  const int kw = w * 256;          // wave's k range

  // Q fragments (B operand: col = q = lo, d = hi*8 + j)
  bf16x8 qf0 = *(const bf16x8*)(q_ws + qk_base + (size_t)(qbase + lo) * 64 + hi * 8);
  bf16x8 qf1 = *(const bf16x8*)(q_ws + qk_base + (size_t)(qbase + lo) * 64 + 32 + hi * 8);

  unsigned p_pk[16][2];            // packed bf16 pairs: k = tile*16 + hi*4 + (0..3), q = lo
  float srow = 0.f;                // partial row sum for q = lo

  // --- Phase 1: QK^T -> exp -> packed regs + row-sum partials ---
#pragma unroll
  for (int t2 = 0; t2 < 16; ++t2) {
    const int cb = kw + t2 * 16;
    const unsigned short* kp = k_ws + qk_base + (size_t)(cb + lo) * 64 + hi * 8;
    bf16x8 kf0 = *(const bf16x8*)kp;
    bf16x8 kf1 = *(const bf16x8*)(kp + 32);
    f32x4 c = {};
    c = MFMA16(kf0, qf0, c);
    c = MFMA16(kf1, qf1, c);
    float e0 = __expf(c[0] * 0.125f);
    float e1 = __expf(c[1] * 0.125f);
    float e2 = __expf(c[2] * 0.125f);
    float e3 = __expf(c[3] * 0.125f);
    srow += (e0 + e1) + (e2 + e3);
    p_pk[t2][0] = (unsigned)f2bf(e0) | ((unsigned)f2bf(e1) << 16);
    p_pk[t2][1] = (unsigned)f2bf(e2) | ((unsigned)f2bf(e3) << 16);
  }

  // --- Phase 2: denominator (lanes sharing lo hold partials for same q) ---
  srow += __shfl_xor(srow, 16, 64);
  srow += __shfl_xor(srow, 32, 64);
  if (hi == 0) wsum[w][lo] = srow;
  __syncthreads();
  if (t < 16) {
    float s = 0.f;
#pragma unroll
    for (int ww = 0; ww < 8; ++ww) s += wsum[ww][t];
    rinv_s[t] = 1.0f / s;
  }
  __syncthreads();

  // --- Phase 3: normalize -> nt store attn + PV MFMA (fused, overlapped) ---
  f32x4 o_acc[4] = {};             // [hd-tile]: rows q = hi*4+i, col hd = hdt*16+lo
  {
    const float rv = rinv_s[lo];
    float* ao = attn_out + (size_t)bh * 2048 * 2048 +
                (size_t)(qbase + lo) * 2048 + kw + hi * 4;
#pragma unroll
    for (int tp = 0; tp < 8; ++tp) {
      const int cb = kw + tp * 32;
      unsigned a0 = p_pk[2 * tp][0], a1 = p_pk[2 * tp][1];
      unsigned b0 = p_pk[2 * tp + 1][0], b1 = p_pk[2 * tp + 1][1];
      // normalized f32 values
      float n0 = bf2f((unsigned short)(a0 & 0xffffu)) * rv;
      float n1 = bf2f((unsigned short)(a0 >> 16)) * rv;
      float n2 = bf2f((unsigned short)(a1 & 0xffffu)) * rv;
      float n3 = bf2f((unsigned short)(a1 >> 16)) * rv;
      float n4 = bf2f((unsigned short)(b0 & 0xffffu)) * rv;
      float n5 = bf2f((unsigned short)(b0 >> 16)) * rv;
      float n6 = bf2f((unsigned short)(b1 & 0xffffu)) * rv;
      float n7 = bf2f((unsigned short)(b1 >> 16)) * rv;
      // attn stores: 2x nontemporal f32x4 (ext-vector type: builtin-legal)
      f32x4 s0; s0[0] = n0; s0[1] = n1; s0[2] = n2; s0[3] = n3;
      f32x4 s1; s1[0] = n4; s1[1] = n5; s1[2] = n6; s1[3] = n7;
      __builtin_nontemporal_store(s0, (f32x4*)(ao + tp * 32));
      __builtin_nontemporal_store(s1, (f32x4*)(ao + tp * 32 + 16));
      // PV A-operand: normalized bf16, slots 0..3 = t2a, 4..7 = t2b
      bf16x8 pa8;
      pa8[0] = (short)f2bf(n0); pa8[1] = (short)f2bf(n1);
      pa8[2] = (short)f2bf(n2); pa8[3] = (short)f2bf(n3);
      pa8[4] = (short)f2bf(n4); pa8[5] = (short)f2bf(n5);
      pa8[6] = (short)f2bf(n6); pa8[7] = (short)f2bf(n7);
#pragma unroll
      for (int hdt = 0; hdt < 4; ++hdt) {
        const unsigned short* vp = vt_ws +
            (size_t)(bh * 64 + hdt * 16 + lo) * 2048 + cb + hi * 4;
        bf16x4 v4a = *(const bf16x4*)vp;
        bf16x4 v4b = *(const bf16x4*)(vp + 16);
        bf16x8 vb8;
        vb8[0] = v4a[0]; vb8[1] = v4a[1]; vb8[2] = v4a[2]; vb8[3] = v4a[3];
        vb8[4] = v4b[0]; vb8[5] = v4b[1]; vb8[6] = v4b[2]; vb8[7] = v4b[3];
        o_acc[hdt] = MFMA16(pa8, vb8, o_acc[hdt]);
      }
    }
  }

  // --- Phase 4: O reduce across waves + write (already normalized) ---
#pragma unroll
  for (int hdt = 0; hdt < 4; ++hdt)
#pragma unroll
    for (int i = 0; i < 4; ++i)
      o_red[w][hi * 4 + i][hdt * 16 + lo] = o_acc[hdt][i];
  __syncthreads();
  {
    const int b_ = bh >> 3, h = bh & 7;
#pragma unroll
    for (int e = 0; e < 2; ++e) {
      int idx = t + e * 512;       // 0..1023 over [16 q][64 hd]
      int q = idx >> 6, hd = idx & 63;
      float s = 0.f;
#pragma unroll
      for (int ww = 0; ww < 8; ++ww) s += o_red[ww][q][hd];
      o_ws[((size_t)(b_ * 2048) + qbase + q) * 512 + h * 64 + hd] = f2bf(s);
    }
  }
}

// ---------------------------------------------------------------------------
// Kernel 3: output projection, f32 out.
// ---------------------------------------------------------------------------
__global__ __launch_bounds__(256) void k_proj_out(
    const unsigned short* __restrict__ Ao, const float* __restrict__ Wo,
    const float* __restrict__ bo, float* __restrict__ outp)
{
  __shared__ unsigned short As[128][72];
  __shared__ unsigned short Bs[128][72];

  const int t = threadIdx.x;
  const int lane = t & 63;
  const int w = t >> 6;
  const int wr = w >> 1, wc = w & 1;
  const int mbase = blockIdx.x * 128;
  const int nbase = blockIdx.y * 128;

  f32x4 acc[4][4] = {};

  for (int kb = 0; kb < 512; kb += 64) {
    __syncthreads();
#pragma unroll
    for (int i = 0; i < 4; ++i) {
      int chunk = i * 256 + t;
      int row = chunk >> 3;
      int c8 = (chunk & 7) * 8;
      *(bf16x8*)&As[row][c8] =
          *(const bf16x8*)(Ao + (size_t)(mbase + row) * 512 + kb + c8);
      const float* gb = Wo + (size_t)(nbase + row) * 512 + kb + c8;
      float4 b0 = *(const float4*)gb;
      float4 b1 = *(const float4*)(gb + 4);
      bf16x8 pb;
      pb[0] = (short)f2bf(b0.x); pb[1] = (short)f2bf(b0.y);
      pb[2] = (short)f2bf(b0.z); pb[3] = (short)f2bf(b0.w);
      pb[4] = (short)f2bf(b1.x); pb[5] = (short)f2bf(b1.y);
      pb[6] = (short)f2bf(b1.z); pb[7] = (short)f2bf(b1.w);
      *(bf16x8*)&Bs[row][c8] = pb;
    }
    __syncthreads();
#pragma unroll
    for (int kk = 0; kk < 64; kk += 32) {
      bf16x8 af[4], bfr[4];
#pragma unroll
      for (int mi = 0; mi < 4; ++mi)
        af[mi] = *(const bf16x8*)&As[wr * 64 + mi * 16 + (lane & 15)][kk + (lane >> 4) * 8];
#pragma unroll
      for (int ni = 0; ni < 4; ++ni)
        bfr[ni] = *(const bf16x8*)&Bs[wc * 64 + ni * 16 + (lane & 15)][kk + (lane >> 4) * 8];
#pragma unroll
      for (int mi = 0; mi < 4; ++mi)
#pragma unroll
        for (int ni = 0; ni < 4; ++ni)
          acc[mi][ni] = MFMA16(af[mi], bfr[ni], acc[mi][ni]);
    }
  }

#pragma unroll
  for (int ni = 0; ni < 4; ++ni) {
    int n = nbase + wc * 64 + ni * 16 + (lane & 15);
    float bv_ = bo[n];
#pragma unroll
    for (int mi = 0; mi < 4; ++mi) {
#pragma unroll
      for (int i = 0; i < 4; ++i) {
        int m = mbase + wr * 64 + mi * 16 + (lane >> 4) * 4 + i;
        outp[(size_t)m * 512 + n] = acc[mi][ni][i] + bv_;
      }
    }
  }
}

// ---------------------------------------------------------------------------
extern "C" void kernel_launch(void* const* d_in, const int* in_sizes, int n_in,
                              void* d_out, int out_size, void* d_ws, size_t ws_size,
                              hipStream_t stream) {
  const float* q_in = (const float*)d_in[0];
  const float* k_in = (const float*)d_in[1];
  const float* v_in = (const float*)d_in[2];
  const float* Wq = (const float*)d_in[3];
  const float* bq = (const float*)d_in[4];
  const float* Wk = (const float*)d_in[5];
  const float* bk = (const float*)d_in[6];
  const float* Wv = (const float*)d_in[7];
  const float* bv = (const float*)d_in[8];
  const float* Wo = (const float*)d_in[9];
  const float* bo = (const float*)d_in[10];

  float* out0 = (float*)d_out;                          // [B,S,D] f32
  float* attn = out0 + (size_t)4 * 2048 * 512;          // [B,H,S,S] f32

  unsigned short* ws = (unsigned short*)d_ws;
  const size_t SEG = (size_t)4 * 2048 * 512;
  unsigned short* q_ws  = ws;
  unsigned short* k_ws  = ws + SEG;
  unsigned short* vt_ws = ws + 2 * SEG;
  unsigned short* o_ws  = ws + 3 * SEG;

  dim3 g1(64, 4, 3);
  k_proj_qkv<<<g1, 256, 0, stream>>>(q_in, k_in, v_in, Wq, bq, Wk, bk, Wv, bv,
                                     q_ws, k_ws, vt_ws);
  dim3 g2(128, 32);
  k_attn<<<g2, 512, 0, stream>>>(q_ws, k_ws, vt_ws, o_ws, attn);
  dim3 g3(64, 4);
  k_proj_out<<<g3, 256, 0, stream>>>(o_ws, Wo, bo, out0);
}